// Round 1
// baseline (291.619 us; speedup 1.0000x reference)
//
#include <hip/hip_runtime.h>
#include <hip/hip_bf16.h>
#include <stdint.h>

// EdgeDecoder: out = relu(concat(zd[row], zt[col]) @ W1 + b1) @ W2 + b2
// R3: pipelined main kernel (T3+T4 minimal 2-phase): 512-thr block, 256-edge
// tile, double-buffered A+B LDS (132KB, 1 block/CU), stage(kc+1) issued
// BEFORE compute(kc), single vmcnt(0)+s_barrier per chunk AFTER compute so
// gather latency hides under 64 MFMA/wave. Swizzle/fragment layout identical
// to R2 (measured 0 bank conflicts). T5 setprio around MFMA cluster.

typedef unsigned short u16;
typedef __attribute__((ext_vector_type(8))) short short8;
typedef __attribute__((ext_vector_type(4))) float f32x4;

#define HDIM 256
#define KDIM 512
#define BM 256     // edges per block
#define BK 64      // k-chunk

__device__ __forceinline__ u16 f2bf(float f) {
  union { float f; uint32_t u; } v; v.f = f;
  uint32_t u = v.u;
  return (u16)((u + 0x7fffu + ((u >> 16) & 1u)) >> 16);   // RNE, inputs finite
}

// async global->LDS, 16B per lane; LDS dest must be wave-uniform base (+lane*16)
__device__ __forceinline__ void gl2lds16(const void* g, void* l) {
  __builtin_amdgcn_global_load_lds(
      (const __attribute__((address_space(1))) unsigned int*)g,
      (__attribute__((address_space(3))) unsigned int*)l,
      16, 0, 0);
}

// One prep kernel: blocks 0..31 do a 64x64 LDS-tiled transpose of W1
// (512x256 fp32 -> W1T 256x512 bf16, coalesced both sides); remaining blocks
// grid-stride-convert zd then zt to bf16 via float4 loads.
#define CVT_BLOCKS 4096
__global__ void prep_kernel(const float* __restrict__ zd_f,
                            const float* __restrict__ zt_f,
                            const float* __restrict__ w1,
                            u16* __restrict__ zdb, u16* __restrict__ ztb,
                            u16* __restrict__ w1t, int n4d, int n4t) {
  const int b = blockIdx.x;
  if (b < 32) {
    __shared__ float tile[64][65];
    const int k0 = (b >> 2) * 64, n0 = (b & 3) * 64;
    const int tx = threadIdx.x & 63, ty = threadIdx.x >> 6;
#pragma unroll
    for (int i = ty; i < 64; i += 4)
      tile[i][tx] = w1[(size_t)(k0 + i) * HDIM + n0 + tx];   // coalesced 256B
    __syncthreads();
#pragma unroll
    for (int i = ty; i < 64; i += 4)
      w1t[(size_t)(n0 + i) * KDIM + k0 + tx] = f2bf(tile[tx][i]);  // coalesced
  } else {
    const int idx = (b - 32) * 256 + threadIdx.x;
    const int stride = CVT_BLOCKS * 256;
    for (int i = idx; i < n4d; i += stride) {
      float4 v = ((const float4*)zd_f)[i];
      ushort4 o; o.x = f2bf(v.x); o.y = f2bf(v.y); o.z = f2bf(v.z); o.w = f2bf(v.w);
      ((ushort4*)zdb)[i] = o;
    }
    for (int i = idx; i < n4t; i += stride) {
      float4 v = ((const float4*)zt_f)[i];
      ushort4 o; o.x = f2bf(v.x); o.y = f2bf(v.y); o.z = f2bf(v.z); o.w = f2bf(v.w);
      ((ushort4*)ztb)[i] = o;
    }
  }
}

// Main fused kernel. Block = 512 thr (8 waves). Tile: 256 edges x 256 cols.
// Wave w: wr=w>>2 edge-half (128 edges), wc=w&3 col-quarter (64 cols) ->
// acc[8][4] 16x16 frags. K-loop: 8 chunks of BK=64 (0-3 zd[row], 4-7 zt[col]),
// double-buffered: stage(kc+1) -> compute(kc) -> vmcnt(0)+barrier.
__global__ __launch_bounds__(512, 2) void edge_mlp_kernel(
    const u16* __restrict__ zd, const u16* __restrict__ zt,
    const int* __restrict__ row, const int* __restrict__ col,
    const u16* __restrict__ w1t, const float* __restrict__ b1,
    const float* __restrict__ w2, const float* __restrict__ b2,
    float* __restrict__ out, int E) {
  __shared__ u16 lA[2][BM * BK];      // 2 x 32KB [edge][k], 16B-slot swizzled
  __shared__ u16 lB[2][HDIM * BK];    // 2 x 32KB [n][k],    16B-slot swizzled
  __shared__ float lP[4 * BM];        // 4KB per-colwave layer-2 partials

  const int tid  = threadIdx.x;
  const int wid  = tid >> 6;                       // 0..7
  const int lane = tid & 63;
  const int e0   = blockIdx.x * BM;
  const int r8   = lane >> 3;                      // row-in-8-group per issue
  const int slog = ((lane & 7) ^ (r8 & 7)) * 8;    // swizzled 16B-slot offset
  const int wr   = wid >> 2;                       // edge-half owned
  const int wc   = wid & 3;                        // col-quarter owned

  // Each wave STAGES 32 edge-rows and 32 n-rows per chunk (8 waves cover 256).
  uint32_t offD[4], offT[4];
#pragma unroll
  for (int t = 0; t < 4; ++t) {
    int ge = min(e0 + wid * 32 + r8 + 8 * t, E - 1);
    offD[t] = (uint32_t)row[ge] * HDIM;
    offT[t] = (uint32_t)col[ge] * HDIM;
  }
  const u16* pB = w1t + (uint32_t)(wid * 32 + r8) * KDIM + slog;

  f32x4 acc[8][4];
#pragma unroll
  for (int i = 0; i < 8; ++i)
#pragma unroll
    for (int j = 0; j < 4; ++j) acc[i][j] = f32x4{0.f, 0.f, 0.f, 0.f};

  const int colid = lane & 15;
  const int quad  = lane >> 4;
  const int csw   = colid & 7;       // read-side swizzle key (row&7 == colid&7)

  auto stage = [&](int kc, int buf) {
    const int koff = (kc & 3) * BK;
    const u16* zbase = (kc < 4) ? zd : zt;
    u16* dA = &lA[buf][(wid * 32) * BK];           // wave-uniform LDS bases
    u16* dB = &lB[buf][(wid * 32) * BK];
#pragma unroll
    for (int t = 0; t < 4; ++t) {
      uint32_t o = (kc < 4) ? offD[t] : offT[t];
      gl2lds16(zbase + o + koff + slog, dA + (8 * t) * BK);
    }
#pragma unroll
    for (int j = 0; j < 4; ++j)
      gl2lds16(pB + (size_t)(j * 8) * KDIM + kc * BK, dB + (j * 8) * BK);
  };

  // Prologue: chunk 0 staged and visible.
  stage(0, 0);
  asm volatile("s_waitcnt vmcnt(0)" ::: "memory");
  __builtin_amdgcn_s_barrier();

  for (int kc = 0; kc < 8; ++kc) {
    const int cur = kc & 1;
    if (kc < 7) stage(kc + 1, cur ^ 1);            // 8 loads in flight
    const u16* A  = lA[cur];
    const u16* Bm = lB[cur];
#pragma unroll
    for (int ks = 0; ks < BK; ks += 32) {
      const int sl = (ks >> 3) + quad;             // logical 16B slot
      short8 aF[8], bF[4];
#pragma unroll
      for (int rt = 0; rt < 8; ++rt)
        aF[rt] = *(const short8*)&A[(wr * 128 + rt * 16 + colid) * BK + ((sl ^ csw) * 8)];
#pragma unroll
      for (int ct = 0; ct < 4; ++ct)
        bF[ct] = *(const short8*)&Bm[(wc * 64 + ct * 16 + colid) * BK + ((sl ^ csw) * 8)];
      __builtin_amdgcn_s_setprio(1);
#pragma unroll
      for (int rt = 0; rt < 8; ++rt)
#pragma unroll
        for (int ct = 0; ct < 4; ++ct)
          acc[rt][ct] = __builtin_amdgcn_mfma_f32_16x16x32_bf16(
              aF[rt], bF[ct], acc[rt][ct], 0, 0, 0);
      __builtin_amdgcn_s_setprio(0);
    }
    // Drain next-chunk loads (overlapped by compute above) + reuse barrier.
    asm volatile("s_waitcnt vmcnt(0)" ::: "memory");
    __builtin_amdgcn_s_barrier();
  }

  // Epilogue: h = relu(acc + b1[n]); partial[e] = sum_n h*W2[n] (fp32)
  // C/D layout: n = wc*64 + ct*16 + colid, e = wr*128 + rt*16 + quad*4 + j
  float b1v[4], w2v[4];
#pragma unroll
  for (int ct = 0; ct < 4; ++ct) {
    int n = wc * 64 + ct * 16 + colid;
    b1v[ct] = b1[n];
    w2v[ct] = w2[n];
  }
#pragma unroll
  for (int rt = 0; rt < 8; ++rt)
#pragma unroll
    for (int j = 0; j < 4; ++j) {
      float s = 0.f;
#pragma unroll
      for (int ct = 0; ct < 4; ++ct)
        s += fmaxf(acc[rt][ct][j] + b1v[ct], 0.f) * w2v[ct];
#pragma unroll
      for (int off = 8; off >= 1; off >>= 1)
        s += __shfl_xor(s, off, 16);               // sum over n within quad-row
      if (colid == 0)
        lP[wc * BM + wr * 128 + rt * 16 + quad * 4 + j] = s;
    }
  __syncthreads();
  if (tid < BM) {
    int ge = e0 + tid;
    if (ge < E)
      out[ge] = lP[tid] + lP[BM + tid] + lP[2 * BM + tid] + lP[3 * BM + tid]
                + b2[0];
  }
}

// Correct-but-slow fp32 fallback (only if ws_size < 36.2MB): 16 edges/block.
__global__ void fallback_kernel(
    const float* __restrict__ zd, const float* __restrict__ zt,
    const int* __restrict__ row, const int* __restrict__ col,
    const float* __restrict__ W1, const float* __restrict__ b1,
    const float* __restrict__ W2, const float* __restrict__ b2,
    float* __restrict__ out, int E) {
  __shared__ float zc[16][512];
  __shared__ float red[4][16];
  const int e0 = blockIdx.x * 16;
  const int tid = threadIdx.x;
  for (int i = tid; i < 16 * 512; i += 256) {
    int e = i >> 9, k = i & 511;
    int ge = min(e0 + e, E - 1);
    zc[e][k] = (k < HDIM) ? zd[(size_t)row[ge] * HDIM + k]
                          : zt[(size_t)col[ge] * HDIM + (k - HDIM)];
  }
  __syncthreads();
  float acc[16];
#pragma unroll
  for (int e = 0; e < 16; ++e) acc[e] = 0.f;
  for (int k = 0; k < KDIM; ++k) {
    float w = W1[k * HDIM + tid];
#pragma unroll
    for (int e = 0; e < 16; ++e) acc[e] += zc[e][k] * w;
  }
  float wv = W2[tid], bv = b1[tid];
  const int lane = tid & 63, wid = tid >> 6;
#pragma unroll
  for (int e = 0; e < 16; ++e) {
    float pv = fmaxf(acc[e] + bv, 0.f) * wv;
#pragma unroll
    for (int off = 32; off >= 1; off >>= 1) pv += __shfl_down(pv, off, 64);
    if (lane == 0) red[wid][e] = pv;
  }
  __syncthreads();
  if (tid < 16) {
    int ge = e0 + tid;
    if (ge < E)
      out[ge] = red[0][tid] + red[1][tid] + red[2][tid] + red[3][tid] + b2[0];
  }
}

extern "C" void kernel_launch(void* const* d_in, const int* in_sizes, int n_in,
                              void* d_out, int out_size, void* d_ws, size_t ws_size,
                              hipStream_t stream) {
  const float* zd_f = (const float*)d_in[0];
  const float* zt_f = (const float*)d_in[1];
  const int*   row  = (const int*)d_in[2];
  const int*   col  = (const int*)d_in[3];
  const float* W1   = (const float*)d_in[4];
  const float* b1   = (const float*)d_in[5];
  const float* W2   = (const float*)d_in[6];
  const float* b2   = (const float*)d_in[7];
  float* out = (float*)d_out;

  const int E  = in_sizes[2];            // 500000
  const int ND = in_sizes[0] / HDIM;     // 50000
  const int NT = in_sizes[1] / HDIM;     // 20000

  size_t off_w1t = 0;                                    // 256KB
  size_t off_zd  = (size_t)KDIM * HDIM * sizeof(u16);
  size_t off_zt  = off_zd + (size_t)ND * HDIM * sizeof(u16);
  size_t need    = off_zt + (size_t)NT * HDIM * sizeof(u16);  // ~36.1MB

  if (ws_size >= need) {
    u16* w1t = (u16*)((char*)d_ws + off_w1t);
    u16* zdb = (u16*)((char*)d_ws + off_zd);
    u16* ztb = (u16*)((char*)d_ws + off_zt);
    int n4d = ND * HDIM / 4, n4t = NT * HDIM / 4;
    prep_kernel<<<32 + CVT_BLOCKS, 256, 0, stream>>>(zd_f, zt_f, W1,
                                                     zdb, ztb, w1t, n4d, n4t);
    edge_mlp_kernel<<<(E + BM - 1) / BM, 512, 0, stream>>>(
        zdb, ztb, row, col, w1t, b1, W2, b2, out, E);
  } else {
    fallback_kernel<<<(E + 15) / 16, 256, 0, stream>>>(
        zd_f, zt_f, row, col, W1, b1, W2, b2, out, E);
  }
}